// Round 7
// baseline (319.800 us; speedup 1.0000x reference)
//
#include <hip/hip_runtime.h>

#define NATOMS 20000
#define NCHAN  64
#define K2 120

// ws layout (bytes) -- total 593920 B:
//   [0 .. 524288)        W2bf bf16[64][4096]  c*4096 + (x*16+y)*16 + i
//   [524288 .. 589824)   W1f  f32 [64][256]   c*256 + x*16 + y
//   [589824 .. 593920)   W0f  f32 [64][16]    c*16 + x
#define W1_OFF_B 524288
#define W0_OFF_B 589824

typedef __attribute__((ext_vector_type(8))) short bf16x8;
typedef __attribute__((ext_vector_type(4))) float f32x4;

__device__ inline short f2bf_rne(float x) {
    union { float f; unsigned u; } v; v.f = x;
    unsigned r = v.u + 0x7FFF + ((v.u >> 16) & 1);
    return (short)(r >> 16);
}
// pack two f32 -> packed bf16 (round-half-up): low16 = a, high16 = b
__device__ inline unsigned pk_bf(float a, float b) {
    unsigned au = __float_as_uint(a) + 0x8000u;
    unsigned bu = __float_as_uint(b) + 0x8000u;
    return __builtin_amdgcn_perm(bu, au, 0x07060302u);
}

// ---------------------------------------------------------------------------
// Kernel 1: fold weights. W2 -> bf16 (MFMA A operand), W1/W0 -> fp32 (exact
// C-preload / epilogue). Same verified mapping as R1/R6.
// ---------------------------------------------------------------------------
__global__ __launch_bounds__(256) void precompute_kernel(
    const float* __restrict__ U2, const float* __restrict__ U1,
    const float* __restrict__ U0, const float* __restrict__ w2,
    const float* __restrict__ w1, const float* __restrict__ w0,
    void* __restrict__ wsv)
{
    short* W2bf = (short*)wsv;
    float* W1f  = (float*)((char*)wsv + W1_OFF_B);
    float* W0f  = (float*)((char*)wsv + W0_OFF_B);
    const int b = blockIdx.x, t = threadIdx.x;

    if (b < 1024) {
        const int row = b * 4 + (t >> 6);         // 0..4095, uniform per wave
        const int c   = t & 63;
        const float* u = U2 + (size_t)row * K2;
        float a0 = 0.f, a1 = 0.f, a2 = 0.f, a3 = 0.f;
        #pragma unroll 6
        for (int k = 0; k < K2; k += 4) {
            a0 += u[k]     * w2[(k)     * NCHAN + c];
            a1 += u[k + 1] * w2[(k + 1) * NCHAN + c];
            a2 += u[k + 2] * w2[(k + 2) * NCHAN + c];
            a3 += u[k + 3] * w2[(k + 3) * NCHAN + c];
        }
        W2bf[c * 4096 + row] = f2bf_rne((a0 + a1) + (a2 + a3));
    } else if (b < 1088) {
        const int id = (b - 1024) * 256 + t;
        const int c = id >> 8, xy = id & 255;
        const float* u = U1 + xy * 8;
        float a = 0.f;
        #pragma unroll
        for (int k = 0; k < 8; ++k) a += u[k] * w1[k * NCHAN + c];
        W1f[c * 256 + xy] = a;
    } else {
        const int id = (b - 1088) * 256 + t;
        const int c = id >> 4, x = id & 15;
        const float* u = U0 + x * 4;
        float a = 0.f;
        #pragma unroll
        for (int k = 0; k < 4; ++k) a += u[k] * w0[k * NCHAN + c];
        W0f[c * 16 + x] = a;
    }
}

// ---------------------------------------------------------------------------
// Kernel 2: block = 32 atoms x 32 channels, 4 waves (wave: 8 ch x 2 tiles).
// Per (ch, tile): 16 independent MFMAs, g = x index:
//   A[row=y][k=i] = W2bf[c][(g*16+y)*16+i]   <- ONE 16B global load per g,
//                                               never stored in an array
//   B[k=i][atom]  = f_bf16[atom][i]          <- built once per tile (4 regs)
//   C[y][atom]    = W1f[c][g*16+y]           <- 16B broadcast load (fp32 exact)
//   D -> lane(q,m): acc[r] = (E+W1)[x=g][y=q*4+r][atom=m]
// Consumed immediately: s += f[g] * sum_r acc[r]*f_y[q*4+r]; W0 in s init;
// cross-q shfl_xor(16,32) completes the y and x sums. NO private arrays other
// than f[16] (all literal indices, fully unrolled) -> nothing can be demoted
// to scratch. R3-R6's 250 MB WRITE_SIZE is theorized to be scratch traffic
// from array demotion (bfr[8]/fi8/fq); this kernel is the discriminating test.
// ---------------------------------------------------------------------------
__global__ __launch_bounds__(256, 1) void contract_kernel(
    const float* __restrict__ nf,   // [N, 64, 16]
    const void* __restrict__ wsv,
    float* __restrict__ out)        // [N, 64]
{
    const short* W2g = (const short*)wsv;
    const float* W1g = (const float*)((const char*)wsv + W1_OFF_B);
    const float* W0g = (const float*)((const char*)wsv + W0_OFF_B);

    __shared__ float Ot[32][33];      // [c_local][atom_local]

    const int tid  = threadIdx.x;
    const int wave = tid >> 6, lane = tid & 63;
    const int m = lane & 15, q = lane >> 4;
    const int c0    = blockIdx.y * 32 + wave * 8;
    const int nBase = blockIdx.x * 32;

    #pragma unroll 1
    for (int ch = 0; ch < 8; ++ch) {
        const int c = c0 + ch;
        const short* Ac  = W2g + (size_t)c * 4096 + m * 16 + q * 8;  // + g*256
        const float* W1c = W1g + c * 256 + q * 4;                    // + g*16
        const float4 w0v = *(const float4*)(W0g + c * 16 + q * 4);

        #pragma unroll 1
        for (int t = 0; t < 2; ++t) {
            const int atom = nBase + t * 16 + m;
            const float* fp = nf + ((size_t)atom * NCHAN + c) * 16;

            float f[16];
            #pragma unroll
            for (int j = 0; j < 4; ++j) {
                float4 v = ((const float4*)fp)[j];
                f[4*j] = v.x; f[4*j+1] = v.y; f[4*j+2] = v.z; f[4*j+3] = v.w;
            }
            const float4 fqv = *(const float4*)(fp + q * 4);  // f_y[q*4+r], fp32

            // B frag: k=q*8+j -> bf16(f[k]) for k<16, zero for k>=16
            float e0 = (q & 1) ? f[8]  : f[0];
            float e1 = (q & 1) ? f[9]  : f[1];
            float e2 = (q & 1) ? f[10] : f[2];
            float e3 = (q & 1) ? f[11] : f[3];
            float e4 = (q & 1) ? f[12] : f[4];
            float e5 = (q & 1) ? f[13] : f[5];
            float e6 = (q & 1) ? f[14] : f[6];
            float e7 = (q & 1) ? f[15] : f[7];
            uint4 bw;
            bw.x = pk_bf(e0, e1); bw.y = pk_bf(e2, e3);
            bw.z = pk_bf(e4, e5); bw.w = pk_bf(e6, e7);
            if (q >= 2) { bw.x = 0u; bw.y = 0u; bw.z = 0u; bw.w = 0u; }
            const bf16x8 bfrag = __builtin_bit_cast(bf16x8, bw);

            // s init: W0 partial (summed over q by the final shfl reduction)
            float s = w0v.x * fqv.x + w0v.y * fqv.y
                    + w0v.z * fqv.z + w0v.w * fqv.w;

            #pragma unroll
            for (int g = 0; g < 16; ++g) {
                bf16x8 af = (bf16x8)0;
                if (q < 2) af = *(const bf16x8*)&Ac[g * 256];
                f32x4 ci = *(const f32x4*)(W1c + g * 16);
                f32x4 acc = __builtin_amdgcn_mfma_f32_16x16x32_bf16(
                                af, bfrag, ci, 0, 0, 0);
                float p = acc[0] * fqv.x + acc[1] * fqv.y
                        + acc[2] * fqv.z + acc[3] * fqv.w;
                s = fmaf(f[g], p, s);
            }

            s += __shfl_xor(s, 16, 64);
            s += __shfl_xor(s, 32, 64);
            if (q == 0) Ot[wave * 8 + ch][t * 16 + m] = s;
        }
    }
    __syncthreads();

    // coalesced writeout: block owns rows nBase..+31, channels c .. c+31
    const int a = tid >> 3, cg = tid & 7;
    float4 v = { Ot[cg*4+0][a], Ot[cg*4+1][a], Ot[cg*4+2][a], Ot[cg*4+3][a] };
    *(float4*)&out[(size_t)(nBase + a) * NCHAN + blockIdx.y * 32 + cg * 4] = v;
}

extern "C" void kernel_launch(void* const* d_in, const int* in_sizes, int n_in,
                              void* d_out, int out_size, void* d_ws, size_t ws_size,
                              hipStream_t stream)
{
    const float* nf = (const float*)d_in[0];
    const float* U2 = (const float*)d_in[1];
    const float* U1 = (const float*)d_in[2];
    const float* U0 = (const float*)d_in[3];
    const float* w2 = (const float*)d_in[4];
    const float* w1 = (const float*)d_in[5];
    const float* w0 = (const float*)d_in[6];
    float* out = (float*)d_out;

    precompute_kernel<<<1092, 256, 0, stream>>>(U2, U1, U0, w2, w1, w0, d_ws);

    dim3 grid(NATOMS / 32, 2);                      // (625, 2), exact cover
    contract_kernel<<<grid, 256, 0, stream>>>(nf, d_ws, out);
}